// Round 13
// baseline (324.497 us; speedup 1.0000x reference)
//
#include <hip/hip_runtime.h>
#include <hip/hip_bf16.h>
#include <cstdint>
#include <cstddef>

// ---- problem constants ----
constexpr int LQc = 1024, LKc = 1024, Bc = 8, Ec = 1024, Hc = 16, Dc = 64;

typedef __bf16 bf16;
typedef __bf16 bf16x4 __attribute__((ext_vector_type(4)));
typedef __bf16 bf16x8 __attribute__((ext_vector_type(8)));
typedef float  f32x4  __attribute__((ext_vector_type(4)));

#define MFMA16(a, b, c) __builtin_amdgcn_mfma_f32_16x16x32_bf16((a), (b), (c), 0, 0, 0)

__device__ __forceinline__ void gload_lds16(const bf16* g, bf16* l) {
  __builtin_amdgcn_global_load_lds((const __attribute__((address_space(1))) void*)g,
                                   (__attribute__((address_space(3))) void*)l, 16, 0, 0);
}

// ============================================================================
// Convert f32 inputs -> bf16, concatenated into ws. query scaled by 0.125.
// ============================================================================
__global__ __launch_bounds__(256) void k_convert(const float* __restrict__ q,
                                                 const float* __restrict__ k,
                                                 const float* __restrict__ wq,
                                                 const float* __restrict__ wkv,
                                                 const float* __restrict__ wout,
                                                 bf16* __restrict__ dst) {
  const size_t i = ((size_t)blockIdx.x * 256 + threadIdx.x) * 8;
  const float* src; size_t off; float sc = 1.0f;
  if (i < 8388608)        { src = q;    off = i; sc = 0.125f; }
  else if (i < 16777216)  { src = k;    off = i - 8388608; }
  else if (i < 17825792)  { src = wq;   off = i - 16777216; }
  else if (i < 19922944)  { src = wkv;  off = i - 17825792; }
  else                    { src = wout; off = i - 19922944; }
  const f32x4 a = *reinterpret_cast<const f32x4*>(src + off);
  const f32x4 b = *reinterpret_cast<const f32x4*>(src + off + 4);
  bf16x8 o;
  o[0] = (bf16)(a.x * sc); o[1] = (bf16)(a.y * sc);
  o[2] = (bf16)(a.z * sc); o[3] = (bf16)(a.w * sc);
  o[4] = (bf16)(b.x * sc); o[5] = (bf16)(b.y * sc);
  o[6] = (bf16)(b.z * sc); o[7] = (bf16)(b.w * sc);
  *reinterpret_cast<bf16x8*>(dst + i) = o;
}

// ============================================================================
// m97-structure bf16 GEMM (R4/R9/R12-exact): 128x128 tile, BK=32, 4 waves 2x2,
// global_load_lds(16B) staging, 2-barrier K-loop, XCD swizzle.
// MODE 0 (fused proj, 1536 blocks): by 0-7: q2@Wq -> qh | 8-15: k2@Wkv lo -> kh
//        | 16-23: k2@Wkv hi -> vh     (HEAD-major [bh][l][d], 32B segments)
// MODE 2 (out proj, 512 blocks): ctx @ Wout -> f32 out (token-major)
// ============================================================================
template <int MODE>
__global__ __launch_bounds__(256) void k_gemm(const bf16* __restrict__ Aq,
                                              const bf16* __restrict__ Ak,
                                              const bf16* __restrict__ Wq,
                                              const bf16* __restrict__ Wkv,
                                              bf16* __restrict__ qh,
                                              bf16* __restrict__ kh,
                                              bf16* __restrict__ vh,
                                              float* __restrict__ o_f) {
  __shared__ bf16 As[128 * 32];
  __shared__ bf16 Bs[128 * 32];

  const int tid  = threadIdx.x;
  const int lane = tid & 63, wave = tid >> 6;
  const int wm = wave & 1, wn = wave >> 1;

  const int cpx = gridDim.x >> 3;
  const int logical = (blockIdx.x & 7) * cpx + (blockIdx.x >> 3);
  const int bx = logical & 63, by = logical >> 6;
  const int m0 = bx * 128;

  const bf16* Ap;
  const bf16* Wp;
  bf16* Op = nullptr;
  if constexpr (MODE == 0) {
    if (by < 8)       { Ap = Aq; Wp = Wq  + (size_t)by * 131072;        Op = qh; }
    else if (by < 16) { Ap = Ak; Wp = Wkv + (size_t)(by - 8) * 131072;  Op = kh; }
    else              { Ap = Ak; Wp = Wkv + 1048576 + (size_t)(by - 16) * 131072; Op = vh; }
  } else {
    Ap = Aq; Wp = Wq + (size_t)by * 131072;
  }
  const int col0 = (by & 7) * 128;

  const int fr = lane & 15, fo = (lane >> 4) * 8;

  f32x4 acc[4][4] = {};

  const int srow = lane >> 2;          // 0..15
  const int scol = (lane & 3) * 8;     // elems
  const bf16* ga = Ap + (size_t)(m0 + wave * 32 + srow) * Ec + scol;
  const bf16* gb = Wp + (size_t)(wave * 32 + srow) * Ec + scol;
  bf16* lA = As + wave * 1024;
  bf16* lB = Bs + wave * 1024;

  for (int k0 = 0; k0 < Ec; k0 += 32) {
    gload_lds16(ga + k0, lA);
    gload_lds16(ga + k0 + 16 * Ec, lA + 512);
    gload_lds16(gb + k0, lB);
    gload_lds16(gb + k0 + 16 * Ec, lB + 512);
    __syncthreads();

    bf16x8 a[4], b[4];
#pragma unroll
    for (int i = 0; i < 4; ++i) {
      a[i] = *reinterpret_cast<const bf16x8*>(As + (wm * 64 + i * 16 + fr) * 32 + fo);
      b[i] = *reinterpret_cast<const bf16x8*>(Bs + (wn * 64 + i * 16 + fr) * 32 + fo);
    }
#pragma unroll
    for (int i = 0; i < 4; ++i)
#pragma unroll
      for (int j = 0; j < 4; ++j) acc[i][j] = MFMA16(a[i], b[j], acc[i][j]);
    __syncthreads();
  }

  const int rb = (lane >> 4) * 4;
#pragma unroll
  for (int i = 0; i < 4; ++i) {
#pragma unroll
    for (int j = 0; j < 4; ++j) {
      const int col = col0 + wn * 64 + j * 16 + fr;
#pragma unroll
      for (int r = 0; r < 4; ++r) {
        const int tok = m0 + wm * 64 + i * 16 + rb + r;
        const float val = acc[i][j][r];
        if constexpr (MODE == 0) {
          const int lq = tok >> 3, bb = tok & 7;
          const int h = col >> 6, dd = col & 63;
          Op[(((size_t)(bb * Hc + h)) * LQc + lq) * Dc + dd] = (bf16)val;
        } else {
          o_f[(size_t)tok * Ec + col] = val;
        }
      }
    }
  }
}

// ============================================================================
// Transpose Vh[bh][lk][64] -> VhT[bh][64][lk], 64x64 LDS tiles (R4/R9-exact)
// ============================================================================
__global__ __launch_bounds__(256) void k_vtrans(const bf16* __restrict__ Vh,
                                                bf16* __restrict__ VhT) {
  __shared__ bf16 tile[64][72];
  const int bh = blockIdx.y;
  const int l0 = blockIdx.x * 64;
  const int r = threadIdx.x >> 3, c = (threadIdx.x & 7) * 8;
#pragma unroll
  for (int rr = 0; rr < 2; ++rr) {
    const int row = rr * 32 + r;
    *reinterpret_cast<bf16x8*>(&tile[row][c]) =
        *reinterpret_cast<const bf16x8*>(Vh + ((size_t)bh * LKc + l0 + row) * Dc + c);
  }
  __syncthreads();
#pragma unroll
  for (int rr = 0; rr < 2; ++rr) {
    const int d = rr * 32 + r;
    bf16x8 o;
#pragma unroll
    for (int j = 0; j < 8; ++j) o[j] = tile[c + j][d];
    *reinterpret_cast<bf16x8*>(VhT + ((size_t)bh * Dc + d) * LKc + l0 + c) = o;
  }
}

// ============================================================================
// Attention (R12 structure + T5 setprio around MFMA clusters): block = (b,h)
// x 32 q-rows, 4 waves. Swapped QK^T (lane holds 4 consecutive k-cols per
// q-row) -> vectorized e stores + f32x4 mask read + 2-shfl row reduce ->
// 1/sum -> parity phase order {prob-write, PV} / {PV, prob-write}, NT prob
// stores, unroll-4 MLP. setprio(1) during MFMA quads/pairs: co-resident
// anti-phased block's store-phase waves yield issue slots (m191 regime).
// ============================================================================
__global__ __launch_bounds__(256) void k_attn(const bf16* __restrict__ Qh,
                                              const bf16* __restrict__ Kh,
                                              const bf16* __restrict__ VhT,
                                              const int* __restrict__ mask,
                                              float* __restrict__ attn_out,
                                              bf16* __restrict__ ctx_out) {
  __shared__ bf16 sP[32][1032];
  __shared__ float smask[1024];
  __shared__ float psum[4][32];
  __shared__ float rinv[32];

  const int tid = threadIdx.x;
  const int lane = tid & 63, wave = tid >> 6;
  const bool pv_first = (blockIdx.x >> 9) & 1;  // generation parity

  int flat = blockIdx.x;                 // 4096 blocks
  flat = (flat & 7) * 512 + (flat >> 3); // XCD swizzle: b == XCD
  const int bh = flat >> 5;
  const int q0 = (flat & 31) * 32;
  const int b = bh >> 4, h = bh & 15;
  const int fr = lane & 15, fo = (lane >> 4) * 8, rb = (lane >> 4) * 4;

#pragma unroll
  for (int c = tid; c < 1024; c += 256)
    smask[c] = mask[b * LKc + c] ? -1e9f : 0.0f;

  // Q fragments from head-major Qh
  bf16x8 qf[2][2];
  const bf16* Qb = Qh + ((size_t)bh * LQc + q0) * Dc;
#pragma unroll
  for (int m = 0; m < 2; ++m)
#pragma unroll
    for (int kc = 0; kc < 2; ++kc)
      qf[m][kc] = *reinterpret_cast<const bf16x8*>(Qb + (size_t)(m * 16 + fr) * Dc + kc * 32 + fo);
  __syncthreads();  // smask ready

  // ---- swapped QK^T: D[k][q]; lane holds q=fr (m0) / 16+fr (m1), k=n+rb+r ----
  const bf16* Kb = Kh + (size_t)bh * LKc * Dc;
  float s0 = 0.f, s1 = 0.f;
#pragma unroll 4
  for (int t = 0; t < 16; ++t) {
    const int n = (wave * 16 + t) * 16;
    const bf16* kp = Kb + (size_t)(n + fr) * Dc + fo;
    const bf16x8 kf0 = *reinterpret_cast<const bf16x8*>(kp);
    const bf16x8 kf1 = *reinterpret_cast<const bf16x8*>(kp + 32);
    f32x4 c0 = {}, c1 = {};
    __builtin_amdgcn_s_setprio(1);
    c0 = MFMA16(kf0, qf[0][0], c0);
    c0 = MFMA16(kf1, qf[0][1], c0);
    c1 = MFMA16(kf0, qf[1][0], c1);
    c1 = MFMA16(kf1, qf[1][1], c1);
    __builtin_amdgcn_s_setprio(0);
    const int kb = n + rb;
    const f32x4 madd = *reinterpret_cast<const f32x4*>(&smask[kb]);
    bf16x4 p0, p1;
#pragma unroll
    for (int r = 0; r < 4; ++r) {
      const float e0 = __expf(c0[r] + madd[r]);
      const float e1 = __expf(c1[r] + madd[r]);
      s0 += e0; s1 += e1;
      p0[r] = (bf16)e0; p1[r] = (bf16)e1;
    }
    *reinterpret_cast<bf16x4*>(&sP[fr][kb])      = p0;
    *reinterpret_cast<bf16x4*>(&sP[16 + fr][kb]) = p1;
  }
  // reduce across the 4 rb-groups (lanes 16 apart, same fr)
  s0 += __shfl_xor(s0, 16, 64); s0 += __shfl_xor(s0, 32, 64);
  s1 += __shfl_xor(s1, 16, 64); s1 += __shfl_xor(s1, 32, 64);
  if (lane < 16) {
    psum[wave][fr]      = s0;
    psum[wave][16 + fr] = s1;
  }
  __syncthreads();
  if (tid < 32)
    rinv[tid] = 1.0f / (psum[0][tid] + psum[1][tid] + psum[2][tid] + psum[3][tid]);
  __syncthreads();

  float* ap = attn_out + ((size_t)bh * LQc + q0) * LKc;
  const bf16* Vb = VhT + ((size_t)bh * Dc + wave * 16 + fr) * LKc;
  f32x4 cacc0 = {}, cacc1 = {};

  if (!pv_first) {
    // ---- prob write then PV ----
#pragma unroll 4
    for (int r = 0; r < 32; ++r) {
      const float rs = rinv[r];
      const bf16x4 v = *reinterpret_cast<const bf16x4*>(&sP[r][tid * 4]);
      f32x4 p;
      p.x = (float)v.x * rs; p.y = (float)v.y * rs;
      p.z = (float)v.z * rs; p.w = (float)v.w * rs;
      __builtin_nontemporal_store(p, reinterpret_cast<f32x4*>(ap + (size_t)r * LKc + tid * 4));
    }
#pragma unroll 4
    for (int kc = 0; kc < 1024; kc += 32) {
      const bf16x8 vf  = *reinterpret_cast<const bf16x8*>(Vb + kc + fo);
      const bf16x8 pa0 = *reinterpret_cast<const bf16x8*>(&sP[fr][kc + fo]);
      const bf16x8 pa1 = *reinterpret_cast<const bf16x8*>(&sP[16 + fr][kc + fo]);
      __builtin_amdgcn_s_setprio(1);
      cacc0 = MFMA16(pa0, vf, cacc0);
      cacc1 = MFMA16(pa1, vf, cacc1);
      __builtin_amdgcn_s_setprio(0);
    }
  } else {
    // ---- PV then prob write ----
#pragma unroll 4
    for (int kc = 0; kc < 1024; kc += 32) {
      const bf16x8 vf  = *reinterpret_cast<const bf16x8*>(Vb + kc + fo);
      const bf16x8 pa0 = *reinterpret_cast<const bf16x8*>(&sP[fr][kc + fo]);
      const bf16x8 pa1 = *reinterpret_cast<const bf16x8*>(&sP[16 + fr][kc + fo]);
      __builtin_amdgcn_s_setprio(1);
      cacc0 = MFMA16(pa0, vf, cacc0);
      cacc1 = MFMA16(pa1, vf, cacc1);
      __builtin_amdgcn_s_setprio(0);
    }
#pragma unroll 4
    for (int r = 0; r < 32; ++r) {
      const float rs = rinv[r];
      const bf16x4 v = *reinterpret_cast<const bf16x4*>(&sP[r][tid * 4]);
      f32x4 p;
      p.x = (float)v.x * rs; p.y = (float)v.y * rs;
      p.z = (float)v.z * rs; p.w = (float)v.w * rs;
      __builtin_nontemporal_store(p, reinterpret_cast<f32x4*>(ap + (size_t)r * LKc + tid * 4));
    }
  }

  const int e = h * Dc + wave * 16 + fr;
#pragma unroll
  for (int r = 0; r < 4; ++r) {
    const int qa = q0 + rb + r;
    ctx_out[((size_t)qa * Bc + b) * Ec + e] = (bf16)(cacc0[r] * rinv[rb + r]);
    const int qb2 = q0 + 16 + rb + r;
    ctx_out[((size_t)qb2 * Bc + b) * Ec + e] = (bf16)(cacc1[r] * rinv[16 + rb + r]);
  }
}

// ============================================================================
extern "C" void kernel_launch(void* const* d_in, const int* in_sizes, int n_in,
                              void* d_out, int out_size, void* d_ws, size_t ws_size,
                              hipStream_t stream) {
  const float* query = (const float*)d_in[0];
  const float* keyx  = (const float*)d_in[1];
  const int*   mask  = (const int*)d_in[2];
  const float* wq    = (const float*)d_in[3];
  const float* wkv   = (const float*)d_in[4];
  const float* wout  = (const float*)d_in[5];

  float* out  = (float*)d_out;                  // (LQ,B,E) flat
  float* attn = out + (size_t)LQc * Bc * Ec;    // (B,H,LQ,LK) flat

  bf16* cvt   = (bf16*)d_ws;
  bf16* q2    = cvt;                    // 8,388,608 (pre-scaled by 0.125)
  bf16* k2    = q2   + 8388608;         // 8,388,608
  bf16* wqb   = k2   + 8388608;         // 1,048,576
  bf16* wkvb  = wqb  + 1048576;         // 2,097,152
  bf16* woutb = wkvb + 2097152;         // 1,048,576
  bf16* qh    = woutb + 1048576;        // 8,388,608 head-major
  bf16* kh    = qh   + 8388608;         // 8,388,608 head-major
  bf16* vh    = kh   + 8388608;         // 8,388,608 head-major
  bf16* vt    = q2;                     // alias: q2 dead after proj gemm
  bf16* ctx   = k2;                     // alias: k2 dead after proj gemm

  k_convert<<<10240, 256, 0, stream>>>(query, keyx, wq, wkv, wout, cvt);
  k_gemm<0><<<1536, 256, 0, stream>>>(q2, k2, wqb, wkvb, qh, kh, vh, nullptr);
  k_vtrans<<<dim3(16, 128), 256, 0, stream>>>(vh, vt);
  k_attn<<<4096, 256, 0, stream>>>(qh, kh, vt, mask, attn, ctx);
  k_gemm<2><<<512, 256, 0, stream>>>(ctx, nullptr, woutb, nullptr, nullptr, nullptr, nullptr, out);
}

// Round 14
// 295.541 us; speedup vs baseline: 1.0980x; 1.0980x over previous
//
#include <hip/hip_runtime.h>
#include <hip/hip_bf16.h>
#include <cstdint>
#include <cstddef>

// ---- problem constants ----
constexpr int LQc = 1024, LKc = 1024, Bc = 8, Ec = 1024, Hc = 16, Dc = 64;

typedef __bf16 bf16;
typedef __bf16 bf16x4 __attribute__((ext_vector_type(4)));
typedef __bf16 bf16x8 __attribute__((ext_vector_type(8)));
typedef float  f32x4  __attribute__((ext_vector_type(4)));

#define MFMA16(a, b, c) __builtin_amdgcn_mfma_f32_16x16x32_bf16((a), (b), (c), 0, 0, 0)

__device__ __forceinline__ void gload_lds16(const bf16* g, bf16* l) {
  __builtin_amdgcn_global_load_lds((const __attribute__((address_space(1))) void*)g,
                                   (__attribute__((address_space(3))) void*)l, 16, 0, 0);
}

// ============================================================================
// Convert f32 inputs -> bf16, concatenated into ws. query scaled by 0.125.
// ============================================================================
__global__ __launch_bounds__(256) void k_convert(const float* __restrict__ q,
                                                 const float* __restrict__ k,
                                                 const float* __restrict__ wq,
                                                 const float* __restrict__ wkv,
                                                 const float* __restrict__ wout,
                                                 bf16* __restrict__ dst) {
  const size_t i = ((size_t)blockIdx.x * 256 + threadIdx.x) * 8;
  const float* src; size_t off; float sc = 1.0f;
  if (i < 8388608)        { src = q;    off = i; sc = 0.125f; }
  else if (i < 16777216)  { src = k;    off = i - 8388608; }
  else if (i < 17825792)  { src = wq;   off = i - 16777216; }
  else if (i < 19922944)  { src = wkv;  off = i - 17825792; }
  else                    { src = wout; off = i - 19922944; }
  const f32x4 a = *reinterpret_cast<const f32x4*>(src + off);
  const f32x4 b = *reinterpret_cast<const f32x4*>(src + off + 4);
  bf16x8 o;
  o[0] = (bf16)(a.x * sc); o[1] = (bf16)(a.y * sc);
  o[2] = (bf16)(a.z * sc); o[3] = (bf16)(a.w * sc);
  o[4] = (bf16)(b.x * sc); o[5] = (bf16)(b.y * sc);
  o[6] = (bf16)(b.z * sc); o[7] = (bf16)(b.w * sc);
  *reinterpret_cast<bf16x8*>(dst + i) = o;
}

// ============================================================================
// m97-structure bf16 GEMM (R4/R9/R12-exact): 128x128 tile, BK=32, 4 waves 2x2,
// global_load_lds(16B) staging, 2-barrier K-loop, XCD swizzle.
// MODE 0 (fused proj, 1536 blocks): by 0-7: q2@Wq -> qh | 8-15: k2@Wkv lo -> kh
//        | 16-23: k2@Wkv hi -> vh     (HEAD-major [bh][l][d], 32B segments)
// MODE 2 (out proj, 512 blocks): ctx @ Wout -> f32 out (token-major)
// ============================================================================
template <int MODE>
__global__ __launch_bounds__(256) void k_gemm(const bf16* __restrict__ Aq,
                                              const bf16* __restrict__ Ak,
                                              const bf16* __restrict__ Wq,
                                              const bf16* __restrict__ Wkv,
                                              bf16* __restrict__ qh,
                                              bf16* __restrict__ kh,
                                              bf16* __restrict__ vh,
                                              float* __restrict__ o_f) {
  __shared__ bf16 As[128 * 32];
  __shared__ bf16 Bs[128 * 32];

  const int tid  = threadIdx.x;
  const int lane = tid & 63, wave = tid >> 6;
  const int wm = wave & 1, wn = wave >> 1;

  const int cpx = gridDim.x >> 3;
  const int logical = (blockIdx.x & 7) * cpx + (blockIdx.x >> 3);
  const int bx = logical & 63, by = logical >> 6;
  const int m0 = bx * 128;

  const bf16* Ap;
  const bf16* Wp;
  bf16* Op = nullptr;
  if constexpr (MODE == 0) {
    if (by < 8)       { Ap = Aq; Wp = Wq  + (size_t)by * 131072;        Op = qh; }
    else if (by < 16) { Ap = Ak; Wp = Wkv + (size_t)(by - 8) * 131072;  Op = kh; }
    else              { Ap = Ak; Wp = Wkv + 1048576 + (size_t)(by - 16) * 131072; Op = vh; }
  } else {
    Ap = Aq; Wp = Wq + (size_t)by * 131072;
  }
  const int col0 = (by & 7) * 128;

  const int fr = lane & 15, fo = (lane >> 4) * 8;

  f32x4 acc[4][4] = {};

  const int srow = lane >> 2;          // 0..15
  const int scol = (lane & 3) * 8;     // elems
  const bf16* ga = Ap + (size_t)(m0 + wave * 32 + srow) * Ec + scol;
  const bf16* gb = Wp + (size_t)(wave * 32 + srow) * Ec + scol;
  bf16* lA = As + wave * 1024;
  bf16* lB = Bs + wave * 1024;

  for (int k0 = 0; k0 < Ec; k0 += 32) {
    gload_lds16(ga + k0, lA);
    gload_lds16(ga + k0 + 16 * Ec, lA + 512);
    gload_lds16(gb + k0, lB);
    gload_lds16(gb + k0 + 16 * Ec, lB + 512);
    __syncthreads();

    bf16x8 a[4], b[4];
#pragma unroll
    for (int i = 0; i < 4; ++i) {
      a[i] = *reinterpret_cast<const bf16x8*>(As + (wm * 64 + i * 16 + fr) * 32 + fo);
      b[i] = *reinterpret_cast<const bf16x8*>(Bs + (wn * 64 + i * 16 + fr) * 32 + fo);
    }
#pragma unroll
    for (int i = 0; i < 4; ++i)
#pragma unroll
      for (int j = 0; j < 4; ++j) acc[i][j] = MFMA16(a[i], b[j], acc[i][j]);
    __syncthreads();
  }

  const int rb = (lane >> 4) * 4;
#pragma unroll
  for (int i = 0; i < 4; ++i) {
#pragma unroll
    for (int j = 0; j < 4; ++j) {
      const int col = col0 + wn * 64 + j * 16 + fr;
#pragma unroll
      for (int r = 0; r < 4; ++r) {
        const int tok = m0 + wm * 64 + i * 16 + rb + r;
        const float val = acc[i][j][r];
        if constexpr (MODE == 0) {
          const int lq = tok >> 3, bb = tok & 7;
          const int h = col >> 6, dd = col & 63;
          Op[(((size_t)(bb * Hc + h)) * LQc + lq) * Dc + dd] = (bf16)val;
        } else {
          o_f[(size_t)tok * Ec + col] = val;
        }
      }
    }
  }
}

// ============================================================================
// Transpose Vh[bh][lk][64] -> VhT[bh][64][lk], 64x64 LDS tiles (R4/R9-exact)
// ============================================================================
__global__ __launch_bounds__(256) void k_vtrans(const bf16* __restrict__ Vh,
                                                bf16* __restrict__ VhT) {
  __shared__ bf16 tile[64][72];
  const int bh = blockIdx.y;
  const int l0 = blockIdx.x * 64;
  const int r = threadIdx.x >> 3, c = (threadIdx.x & 7) * 8;
#pragma unroll
  for (int rr = 0; rr < 2; ++rr) {
    const int row = rr * 32 + r;
    *reinterpret_cast<bf16x8*>(&tile[row][c]) =
        *reinterpret_cast<const bf16x8*>(Vh + ((size_t)bh * LKc + l0 + row) * Dc + c);
  }
  __syncthreads();
#pragma unroll
  for (int rr = 0; rr < 2; ++rr) {
    const int d = rr * 32 + r;
    bf16x8 o;
#pragma unroll
    for (int j = 0; j < 8; ++j) o[j] = tile[c + j][d];
    *reinterpret_cast<bf16x8*>(VhT + ((size_t)bh * Dc + d) * LKc + l0 + c) = o;
  }
}

// ============================================================================
// Attention (R12 structure, NO setprio, wave-level write/PV anti-phase):
// block = (b,h) x 32 q-rows, 4 waves. Swapped QK^T -> vectorized e stores ->
// 1/sum. Then prob-write is partitioned PER WAVE (wave w owns rows w*8..+8,
// 1KB/instr coalesced NT stores); waves with ((wave>>1)^parity)==0 do
// {write, PV}, others {PV, write} -> every CU keeps ~half its waves in MFMA
// and half in store phase at all times (smooth HBM-write demand).
// ============================================================================
__global__ __launch_bounds__(256) void k_attn(const bf16* __restrict__ Qh,
                                              const bf16* __restrict__ Kh,
                                              const bf16* __restrict__ VhT,
                                              const int* __restrict__ mask,
                                              float* __restrict__ attn_out,
                                              bf16* __restrict__ ctx_out) {
  __shared__ bf16 sP[32][1032];
  __shared__ float smask[1024];
  __shared__ float psum[4][32];
  __shared__ float rinv[32];

  const int tid = threadIdx.x;
  const int lane = tid & 63, wave = tid >> 6;
  const int parity = (blockIdx.x >> 9) & 1;     // generation parity

  int flat = blockIdx.x;                 // 4096 blocks
  flat = (flat & 7) * 512 + (flat >> 3); // XCD swizzle: b == XCD
  const int bh = flat >> 5;
  const int q0 = (flat & 31) * 32;
  const int b = bh >> 4, h = bh & 15;
  const int fr = lane & 15, fo = (lane >> 4) * 8, rb = (lane >> 4) * 4;

#pragma unroll
  for (int c = tid; c < 1024; c += 256)
    smask[c] = mask[b * LKc + c] ? -1e9f : 0.0f;

  // Q fragments from head-major Qh
  bf16x8 qf[2][2];
  const bf16* Qb = Qh + ((size_t)bh * LQc + q0) * Dc;
#pragma unroll
  for (int m = 0; m < 2; ++m)
#pragma unroll
    for (int kc = 0; kc < 2; ++kc)
      qf[m][kc] = *reinterpret_cast<const bf16x8*>(Qb + (size_t)(m * 16 + fr) * Dc + kc * 32 + fo);
  __syncthreads();  // smask ready

  // ---- swapped QK^T: D[k][q]; lane holds q=fr (m0) / 16+fr (m1), k=n+rb+r ----
  const bf16* Kb = Kh + (size_t)bh * LKc * Dc;
  float s0 = 0.f, s1 = 0.f;
#pragma unroll 4
  for (int t = 0; t < 16; ++t) {
    const int n = (wave * 16 + t) * 16;
    const bf16* kp = Kb + (size_t)(n + fr) * Dc + fo;
    const bf16x8 kf0 = *reinterpret_cast<const bf16x8*>(kp);
    const bf16x8 kf1 = *reinterpret_cast<const bf16x8*>(kp + 32);
    f32x4 c0 = {}, c1 = {};
    c0 = MFMA16(kf0, qf[0][0], c0);
    c0 = MFMA16(kf1, qf[0][1], c0);
    c1 = MFMA16(kf0, qf[1][0], c1);
    c1 = MFMA16(kf1, qf[1][1], c1);
    const int kb = n + rb;
    const f32x4 madd = *reinterpret_cast<const f32x4*>(&smask[kb]);
    bf16x4 p0, p1;
#pragma unroll
    for (int r = 0; r < 4; ++r) {
      const float e0 = __expf(c0[r] + madd[r]);
      const float e1 = __expf(c1[r] + madd[r]);
      s0 += e0; s1 += e1;
      p0[r] = (bf16)e0; p1[r] = (bf16)e1;
    }
    *reinterpret_cast<bf16x4*>(&sP[fr][kb])      = p0;
    *reinterpret_cast<bf16x4*>(&sP[16 + fr][kb]) = p1;
  }
  // reduce across the 4 rb-groups (lanes 16 apart, same fr)
  s0 += __shfl_xor(s0, 16, 64); s0 += __shfl_xor(s0, 32, 64);
  s1 += __shfl_xor(s1, 16, 64); s1 += __shfl_xor(s1, 32, 64);
  if (lane < 16) {
    psum[wave][fr]      = s0;
    psum[wave][16 + fr] = s1;
  }
  __syncthreads();
  if (tid < 32)
    rinv[tid] = 1.0f / (psum[0][tid] + psum[1][tid] + psum[2][tid] + psum[3][tid]);
  __syncthreads();

  float* ap = attn_out + ((size_t)bh * LQc + q0) * LKc;
  const bf16* Vb = VhT + ((size_t)bh * Dc + wave * 16 + fr) * LKc;
  f32x4 cacc0 = {}, cacc1 = {};

  const int wrbase = wave * 8;                      // this wave's 8 write rows
  const bool write_first = (((wave >> 1) & 1) ^ parity) == 0;

  if (write_first) {
    // ---- this wave: prob write (its 8 rows) then PV ----
#pragma unroll 2
    for (int rr = 0; rr < 8; ++rr) {
      const int r = wrbase + rr;
      const float rs = rinv[r];
#pragma unroll
      for (int ch = 0; ch < 4; ++ch) {
        const bf16x4 v = *reinterpret_cast<const bf16x4*>(&sP[r][ch * 256 + lane * 4]);
        f32x4 p;
        p.x = (float)v.x * rs; p.y = (float)v.y * rs;
        p.z = (float)v.z * rs; p.w = (float)v.w * rs;
        __builtin_nontemporal_store(p,
            reinterpret_cast<f32x4*>(ap + (size_t)r * LKc + ch * 256 + lane * 4));
      }
    }
#pragma unroll 4
    for (int kc = 0; kc < 1024; kc += 32) {
      const bf16x8 vf  = *reinterpret_cast<const bf16x8*>(Vb + kc + fo);
      const bf16x8 pa0 = *reinterpret_cast<const bf16x8*>(&sP[fr][kc + fo]);
      const bf16x8 pa1 = *reinterpret_cast<const bf16x8*>(&sP[16 + fr][kc + fo]);
      cacc0 = MFMA16(pa0, vf, cacc0);
      cacc1 = MFMA16(pa1, vf, cacc1);
    }
  } else {
    // ---- this wave: PV then prob write (its 8 rows) ----
#pragma unroll 4
    for (int kc = 0; kc < 1024; kc += 32) {
      const bf16x8 vf  = *reinterpret_cast<const bf16x8*>(Vb + kc + fo);
      const bf16x8 pa0 = *reinterpret_cast<const bf16x8*>(&sP[fr][kc + fo]);
      const bf16x8 pa1 = *reinterpret_cast<const bf16x8*>(&sP[16 + fr][kc + fo]);
      cacc0 = MFMA16(pa0, vf, cacc0);
      cacc1 = MFMA16(pa1, vf, cacc1);
    }
#pragma unroll 2
    for (int rr = 0; rr < 8; ++rr) {
      const int r = wrbase + rr;
      const float rs = rinv[r];
#pragma unroll
      for (int ch = 0; ch < 4; ++ch) {
        const bf16x4 v = *reinterpret_cast<const bf16x4*>(&sP[r][ch * 256 + lane * 4]);
        f32x4 p;
        p.x = (float)v.x * rs; p.y = (float)v.y * rs;
        p.z = (float)v.z * rs; p.w = (float)v.w * rs;
        __builtin_nontemporal_store(p,
            reinterpret_cast<f32x4*>(ap + (size_t)r * LKc + ch * 256 + lane * 4));
      }
    }
  }

  const int e = h * Dc + wave * 16 + fr;
#pragma unroll
  for (int r = 0; r < 4; ++r) {
    const int qa = q0 + rb + r;
    ctx_out[((size_t)qa * Bc + b) * Ec + e] = (bf16)(cacc0[r] * rinv[rb + r]);
    const int qb2 = q0 + 16 + rb + r;
    ctx_out[((size_t)qb2 * Bc + b) * Ec + e] = (bf16)(cacc1[r] * rinv[16 + rb + r]);
  }
}

// ============================================================================
extern "C" void kernel_launch(void* const* d_in, const int* in_sizes, int n_in,
                              void* d_out, int out_size, void* d_ws, size_t ws_size,
                              hipStream_t stream) {
  const float* query = (const float*)d_in[0];
  const float* keyx  = (const float*)d_in[1];
  const int*   mask  = (const int*)d_in[2];
  const float* wq    = (const float*)d_in[3];
  const float* wkv   = (const float*)d_in[4];
  const float* wout  = (const float*)d_in[5];

  float* out  = (float*)d_out;                  // (LQ,B,E) flat
  float* attn = out + (size_t)LQc * Bc * Ec;    // (B,H,LQ,LK) flat

  bf16* cvt   = (bf16*)d_ws;
  bf16* q2    = cvt;                    // 8,388,608 (pre-scaled by 0.125)
  bf16* k2    = q2   + 8388608;         // 8,388,608
  bf16* wqb   = k2   + 8388608;         // 1,048,576
  bf16* wkvb  = wqb  + 1048576;         // 2,097,152
  bf16* woutb = wkvb + 2097152;         // 1,048,576
  bf16* qh    = woutb + 1048576;        // 8,388,608 head-major
  bf16* kh    = qh   + 8388608;         // 8,388,608 head-major
  bf16* vh    = kh   + 8388608;         // 8,388,608 head-major
  bf16* vt    = q2;                     // alias: q2 dead after proj gemm
  bf16* ctx   = k2;                     // alias: k2 dead after proj gemm

  k_convert<<<10240, 256, 0, stream>>>(query, keyx, wq, wkv, wout, cvt);
  k_gemm<0><<<1536, 256, 0, stream>>>(q2, k2, wqb, wkvb, qh, kh, vh, nullptr);
  k_vtrans<<<dim3(16, 128), 256, 0, stream>>>(vh, vt);
  k_attn<<<4096, 256, 0, stream>>>(qh, kh, vt, mask, attn, ctx);
  k_gemm<2><<<512, 256, 0, stream>>>(ctx, nullptr, woutb, nullptr, nullptr, nullptr, nullptr, out);
}